// Round 12
// baseline (97.628 us; speedup 1.0000x reference)
//
#include <hip/hip_runtime.h>
#include <hip/hip_bf16.h>
#include <math.h>

typedef __attribute__((ext_vector_type(8))) __bf16 bf16x8;
typedef __attribute__((ext_vector_type(4))) __bf16 bf16x4;
typedef __attribute__((ext_vector_type(4))) float f32x4;

#define EE 1024
#define HH 16
#define DD 64
#define BB 8
#define TT 64
#define NSPLIT 8

__device__ __forceinline__ f32x4 mfma16(bf16x8 a, bf16x8 b, f32x4 c) {
    return __builtin_amdgcn_mfma_f32_16x16x32_bf16(a, b, c, 0, 0, 0);
}

// ---- prep: weight transpose+convert (WT[w][n][k] bf16, all 4 weights) ----
__global__ __launch_bounds__(256) void k_prep(const float* __restrict__ Wq, const float* __restrict__ Wk,
                                              const float* __restrict__ Wv, const float* __restrict__ Wo,
                                              __bf16* __restrict__ WT) {
    __shared__ float tile[64][68];
    int bid = blockIdx.x;           // 0..1023
    int w = bid >> 8, tl = bid & 255;
    int k0 = (tl >> 4) * 64, n0 = (tl & 15) * 64;
    const float* W = (w == 0) ? Wq : (w == 1) ? Wk : (w == 2) ? Wv : Wo;
    int tid = threadIdx.x;
#pragma unroll
    for (int p = 0; p < 4; ++p) {
        int idx = p * 256 + tid;
        int r = idx >> 4, c4 = (idx & 15) * 4;
        float4 f = *(const float4*)&W[(size_t)(k0 + r) * EE + n0 + c4];
        *(float4*)&tile[r][c4] = f;
    }
    __syncthreads();
    __bf16* out = WT + (size_t)w * EE * EE;
#pragma unroll
    for (int p = 0; p < 2; ++p) {
        int q = p * 256 + tid;
        int r = q >> 3, c8 = (q & 7) * 8;
        bf16x8 v;
#pragma unroll
        for (int j = 0; j < 8; ++j) v[j] = (__bf16)tile[c8 + j][r];
        *(bf16x8*)&out[(size_t)(n0 + r) * EE + k0 + c8] = v;
    }
}

// ---- fused QKV projection + RoPE: x f32-direct (A), WT bf16 (B); R10 exact ----
__global__ __launch_bounds__(256) void k_qkv(const float* __restrict__ x, const __bf16* __restrict__ WT,
                                             const int* __restrict__ sp_ptr,
                                             __bf16* __restrict__ qws, __bf16* __restrict__ knew,
                                             __bf16* __restrict__ vnew) {
    __shared__ __bf16 a_lds[64][72];
    __shared__ __bf16 b_lds[64][72];
    __shared__ float cs_l[32], sn_l[32];
    int xcd = blockIdx.x & 7, idx = blockIdx.x >> 3;
    int bn = xcd * 6 + idx % 6;
    int bm = idx / 6;
    int wsel = bn >> 4;              // 0=q, 1=k, 2=v
    int n0 = (bn & 15) * 64;
    int m0 = bm * 64;
    const __bf16* Wt = WT + (size_t)wsel * EE * EE;
    int tid = threadIdx.x;
    int wv = tid >> 6, lane = tid & 63;
    int l16 = lane & 15, lhi = lane >> 4;
    int g = tid >> 4, m4 = (tid & 15) * 4;   // A staging (f32 rows)
    int r0 = tid >> 3, c8 = (tid & 7) * 8;   // B staging (bf16 rows)

    f32x4 acc[4];
#pragma unroll
    for (int f = 0; f < 4; ++f) acc[f] = (f32x4){0.f, 0.f, 0.f, 0.f};

    f32x4 areg[4];
    bf16x8 br0, br1;
#pragma unroll
    for (int p = 0; p < 4; ++p)
        areg[p] = *(const f32x4*)&x[(size_t)(m0 + p * 16 + g) * EE + m4];
    br0 = *(const bf16x8*)&Wt[(size_t)(n0 + r0) * EE + c8];
    br1 = *(const bf16x8*)&Wt[(size_t)(n0 + 32 + r0) * EE + c8];

    if (tid < 32) {
        int h = bn & 15;
        int sp = sp_ptr[0];
        float invf = powf(10000.0f, -(float)tid / 32.0f);
        float ang = (float)(sp + h) * invf;
        float s, c;
        sincosf(ang, &s, &c);
        cs_l[tid] = c;
        sn_l[tid] = s;
    }

    for (int kt = 0; kt < 16; ++kt) {
        __syncthreads();
#pragma unroll
        for (int p = 0; p < 4; ++p) {
            bf16x4 a4 = { (__bf16)areg[p][0], (__bf16)areg[p][1], (__bf16)areg[p][2], (__bf16)areg[p][3] };
            *(bf16x4*)&a_lds[p * 16 + g][m4] = a4;
        }
        *(bf16x8*)&b_lds[r0][c8] = br0;
        *(bf16x8*)&b_lds[32 + r0][c8] = br1;
        if (kt < 15) {
            int ko = (kt + 1) * 64;
#pragma unroll
            for (int p = 0; p < 4; ++p)
                areg[p] = *(const f32x4*)&x[(size_t)(m0 + p * 16 + g) * EE + ko + m4];
            br0 = *(const bf16x8*)&Wt[(size_t)(n0 + r0) * EE + ko + c8];
            br1 = *(const bf16x8*)&Wt[(size_t)(n0 + 32 + r0) * EE + ko + c8];
        }
        __syncthreads();
        bf16x8 a0 = *(bf16x8*)&a_lds[wv * 16 + l16][lhi * 8];
        bf16x8 a1 = *(bf16x8*)&a_lds[wv * 16 + l16][32 + lhi * 8];
#pragma unroll
        for (int f = 0; f < 4; ++f) {
            bf16x8 b0 = *(bf16x8*)&b_lds[f * 16 + l16][lhi * 8];
            bf16x8 b1 = *(bf16x8*)&b_lds[f * 16 + l16][32 + lhi * 8];
            acc[f] = mfma16(a0, b0, acc[f]);
            acc[f] = mfma16(a1, b1, acc[f]);
        }
    }
    __bf16* dst = (wsel == 0) ? qws : (wsel == 1) ? knew : vnew;
    int h = bn & 15;
#pragma unroll
    for (int f = 0; f < 4; ++f) {
#pragma unroll
        for (int r = 0; r < 4; ++r) {
            float v = acc[f][r];
            int row = m0 + wv * 16 + lhi * 4 + r;
            int d = f * 16 + l16;
            float o = v;
            if (wsel < 2) {
                float other = __shfl_xor(v, 1);
                int pp = d >> 1;
                float c = cs_l[pp], s = sn_l[pp];
                o = ((d & 1) == 0) ? (v * c - other * s) : (other * s + v * c);
            }
            int b = row >> 6, t = row & 63;
            dst[((size_t)((b * HH + h) * TT + t)) * DD + d] = (__bf16)o;
        }
    }
}

// ---- flash-decoding attention: R10 exact (structure + strides) ----
__global__ __launch_bounds__(256, 4) void k_attn(const __bf16* __restrict__ qws, const __bf16* __restrict__ knew,
                                                 const __bf16* __restrict__ vnew,
                                                 const float* __restrict__ ck, const float* __restrict__ cv,
                                                 __bf16* __restrict__ Opart, float* __restrict__ lpart) {
    __shared__ __bf16 k_lds[64][72];    // [s][d]
    __shared__ __bf16 vT_lds[64][68];   // [d][s]
    __shared__ __bf16 p_lds[64][72];    // [t][s] (wave-local rows)
    int bh = blockIdx.x >> 3, split = blockIdx.x & 7;
    int b = bh >> 4, h = bh & 15;
    int tid = threadIdx.x, wv = tid >> 6, lane = tid & 63;
    int l16 = lane & 15, lhi = lane >> 4;
    int g = tid >> 4, m4 = (tid & 15) * 4;

    bf16x8 qf0, qf1;
    {
        const __bf16* qp = qws + ((size_t)bh * TT + (wv * 16 + l16)) * DD;
        qf0 = *(const bf16x8*)&qp[lhi * 8];
        qf1 = *(const bf16x8*)&qp[32 + lhi * 8];
    }
    f32x4 acc[4];
#pragma unroll
    for (int f = 0; f < 4; ++f) acc[f] = (f32x4){0.f, 0.f, 0.f, 0.f};
    float l[4] = {0.f, 0.f, 0.f, 0.f};

    const float* ckb = ck + (size_t)b * 8192 * EE + h * DD;
    const float* cvb = cv + (size_t)b * 8192 * EE + h * DD;
    int s0 = split * 512;

    auto compute = [&](bool mask) {
        f32x4 sf[4];
#pragma unroll
        for (int f = 0; f < 4; ++f) {
            f32x4 z = (f32x4){0.f, 0.f, 0.f, 0.f};
            bf16x8 b0 = *(bf16x8*)&k_lds[f * 16 + l16][lhi * 8];
            bf16x8 b1 = *(bf16x8*)&k_lds[f * 16 + l16][32 + lhi * 8];
            z = mfma16(qf0, b0, z);
            z = mfma16(qf1, b1, z);
            sf[f] = z;
        }
        const float SC = 0.125f * 1.44269504f;
#pragma unroll
        for (int f = 0; f < 4; ++f) {
#pragma unroll
            for (int r = 0; r < 4; ++r) {
                float sv = sf[f][r] * SC;
                if (mask) {
                    int t_row = wv * 16 + lhi * 4 + r;
                    int s_loc = f * 16 + l16;
                    if (s_loc > t_row) sv = -1e30f;
                }
                float pv = exp2f(sv);
                sf[f][r] = pv;
                l[r] += pv;
            }
        }
#pragma unroll
        for (int f = 0; f < 4; ++f)
#pragma unroll
            for (int r = 0; r < 4; ++r)
                p_lds[wv * 16 + lhi * 4 + r][f * 16 + l16] = (__bf16)sf[f][r];
        bf16x8 pa0 = *(bf16x8*)&p_lds[wv * 16 + l16][lhi * 8];
        bf16x8 pa1 = *(bf16x8*)&p_lds[wv * 16 + l16][32 + lhi * 8];
#pragma unroll
        for (int f = 0; f < 4; ++f) {
            bf16x8 v0 = *(bf16x8*)&vT_lds[f * 16 + l16][lhi * 8];
            bf16x8 v1 = *(bf16x8*)&vT_lds[f * 16 + l16][32 + lhi * 8];
            acc[f] = mfma16(pa0, v0, acc[f]);
            acc[f] = mfma16(pa1, v1, acc[f]);
        }
    };

    f32x4 kreg[4], vreg[4];
#pragma unroll
    for (int p = 0; p < 4; ++p)
        kreg[p] = *(const f32x4*)&ckb[(size_t)(s0 + p * 16 + g) * EE + m4];
#pragma unroll
    for (int i = 0; i < 4; ++i)
        vreg[i] = *(const f32x4*)&cvb[(size_t)(s0 + 4 * g + i) * EE + m4];

    for (int it = 0; it < 8; ++it) {
#pragma unroll
        for (int p = 0; p < 4; ++p) {
            bf16x4 k4 = { (__bf16)kreg[p][0], (__bf16)kreg[p][1], (__bf16)kreg[p][2], (__bf16)kreg[p][3] };
            *(bf16x4*)&k_lds[p * 16 + g][m4] = k4;
        }
#pragma unroll
        for (int j = 0; j < 4; ++j) {
            bf16x4 tv = { (__bf16)vreg[0][j], (__bf16)vreg[1][j], (__bf16)vreg[2][j], (__bf16)vreg[3][j] };
            *(bf16x4*)&vT_lds[m4 + j][4 * g] = tv;
        }
        if (it < 7) {                // pre-barrier prefetch (proven position)
            int sb = s0 + (it + 1) * 64;
#pragma unroll
            for (int p = 0; p < 4; ++p)
                kreg[p] = *(const f32x4*)&ckb[(size_t)(sb + p * 16 + g) * EE + m4];
#pragma unroll
            for (int i = 0; i < 4; ++i)
                vreg[i] = *(const f32x4*)&cvb[(size_t)(sb + 4 * g + i) * EE + m4];
        }
        __syncthreads();
        compute(false);
        __syncthreads();
    }

    if (split == 7) {
#pragma unroll
        for (int p = 0; p < 2; ++p) {
            int idx = p * 256 + tid;
            int r = idx >> 3, c8 = (idx & 7) * 8;
            *(bf16x8*)&k_lds[r][c8] = *(const bf16x8*)&knew[((size_t)bh * TT + r) * DD + c8];
            bf16x8 vf = *(const bf16x8*)&vnew[((size_t)bh * TT + r) * DD + c8];
#pragma unroll
            for (int j = 0; j < 8; ++j) vT_lds[c8 + j][r] = vf[j];
        }
        __syncthreads();
        compute(true);
    }

#pragma unroll
    for (int off = 1; off < 16; off <<= 1) {
#pragma unroll
        for (int r = 0; r < 4; ++r) l[r] += __shfl_xor(l[r], off);
    }

#pragma unroll
    for (int f = 0; f < 4; ++f)
#pragma unroll
        for (int r = 0; r < 4; ++r) {
            int t = wv * 16 + lhi * 4 + r;
            int d = f * 16 + l16;
            Opart[(((size_t)split * 128 + bh) * TT + t) * DD + d] = (__bf16)acc[f][r];
        }
    if (l16 == 0) {
#pragma unroll
        for (int r = 0; r < 4; ++r) {
            int t = wv * 16 + lhi * 4 + r;
            lpart[((size_t)split * 128 + bh) * TT + t] = l[r];
        }
    }
}

// ---- fused combine + output projection ----
// grid = 256 (XCD-swizzled): bn 0..31 (N=32 panel), bm = batch 0..7.
// A-tile for K-step kt == ctx(batch, head kt): built on the fly by summing the
// 8 Opart splits (no-max combine) with the same pre-barrier prefetch slot the
// ctxb loads used. Opart re-reads are L3-resident (8.4 MB).
__global__ __launch_bounds__(256) void k_oproj(const __bf16* __restrict__ Opart, const float* __restrict__ lpart,
                                               const __bf16* __restrict__ WoT, float* __restrict__ out) {
    __shared__ __bf16 a_lds[64][72];
    __shared__ __bf16 b_lds[32][72];
    int xcd = blockIdx.x & 7, idx = blockIdx.x >> 3;   // idx 0..31
    int bn = xcd * 4 + (idx & 3);   // 0..31
    int bq = idx >> 2;              // 0..7 = batch
    int n0 = bn * 32;
    int tid = threadIdx.x;
    int wv = tid >> 6, lane = tid & 63;
    int l16 = lane & 15, lhi = lane >> 4;
    int r0 = tid >> 3, c8 = (tid & 7) * 8;   // staging rows (A: r0 and r0+32; B: r0)
    int mo = wv * 16;
    f32x4 acc[2];
#pragma unroll
    for (int f = 0; f < 2; ++f) acc[f] = (f32x4){0.f, 0.f, 0.f, 0.f};

    bf16x8 oreg[2][8];
    float dr[2][8];
    bf16x8 brg;
    auto loadA = [&](int head) {
        int bh = bq * 16 + head;
#pragma unroll
        for (int rp = 0; rp < 2; ++rp) {
            int t = r0 + rp * 32;
#pragma unroll
            for (int s = 0; s < 8; ++s) {
                size_t base = ((size_t)(s * 128 + bh) * TT + t);
                oreg[rp][s] = *(const bf16x8*)&Opart[base * DD + c8];
                dr[rp][s] = lpart[base];
            }
        }
    };
    loadA(0);
    brg = *(const bf16x8*)&WoT[(size_t)(n0 + r0) * EE + c8];

    for (int kt = 0; kt < 16; ++kt) {
        __syncthreads();
        // stage A: combine 8 splits -> normalized bf16 ctx tile
#pragma unroll
        for (int rp = 0; rp < 2; ++rp) {
            float num[8] = {0.f, 0.f, 0.f, 0.f, 0.f, 0.f, 0.f, 0.f};
            float den = 0.f;
#pragma unroll
            for (int s = 0; s < 8; ++s) {
                den += dr[rp][s];
#pragma unroll
                for (int j = 0; j < 8; ++j) num[j] += (float)oreg[rp][s][j];
            }
            float inv = 1.0f / den;
            bf16x8 a;
#pragma unroll
            for (int j = 0; j < 8; ++j) a[j] = (__bf16)(num[j] * inv);
            *(bf16x8*)&a_lds[r0 + rp * 32][c8] = a;
        }
        *(bf16x8*)&b_lds[r0][c8] = brg;
        if (kt < 15) {               // pre-barrier prefetch (proven position)
            loadA(kt + 1);
            brg = *(const bf16x8*)&WoT[(size_t)(n0 + r0) * EE + (kt + 1) * 64 + c8];
        }
        __syncthreads();
        bf16x8 a0 = *(bf16x8*)&a_lds[mo + l16][lhi * 8];
        bf16x8 a1 = *(bf16x8*)&a_lds[mo + l16][32 + lhi * 8];
#pragma unroll
        for (int f = 0; f < 2; ++f) {
            bf16x8 b0 = *(bf16x8*)&b_lds[f * 16 + l16][lhi * 8];
            bf16x8 b1 = *(bf16x8*)&b_lds[f * 16 + l16][32 + lhi * 8];
            acc[f] = mfma16(a0, b0, acc[f]);
            acc[f] = mfma16(a1, b1, acc[f]);
        }
    }
#pragma unroll
    for (int f = 0; f < 2; ++f)
#pragma unroll
        for (int r = 0; r < 4; ++r) {
            int row = bq * 64 + mo + lhi * 4 + r;
            out[(size_t)row * EE + n0 + f * 16 + l16] = acc[f][r];
        }
}

extern "C" void kernel_launch(void* const* d_in, const int* in_sizes, int n_in,
                              void* d_out, int out_size, void* d_ws, size_t ws_size,
                              hipStream_t stream) {
    const float* x  = (const float*)d_in[0];
    const float* ck = (const float*)d_in[1];
    const float* cv = (const float*)d_in[2];
    const float* Wq = (const float*)d_in[3];
    const float* Wk = (const float*)d_in[4];
    const float* Wv = (const float*)d_in[5];
    const float* Wo = (const float*)d_in[6];
    const int* sp   = (const int*)d_in[7];
    float* out = (float*)d_out;

    char* p = (char*)d_ws;
    __bf16* WT = (__bf16*)p;            p += (size_t)4 * 1024 * 1024 * 2;
    __bf16* qws = (__bf16*)p;           p += (size_t)524288 * 2;
    __bf16* knew = (__bf16*)p;          p += (size_t)524288 * 2;
    __bf16* vnew = (__bf16*)p;          p += (size_t)524288 * 2;
    __bf16* Opart = (__bf16*)p;         p += (size_t)NSPLIT * 128 * 64 * 64 * 2;
    float* lpart = (float*)p;           p += (size_t)NSPLIT * 8192 * 4;

    k_prep<<<1024, 256, 0, stream>>>(Wq, Wk, Wv, Wo, WT);
    k_qkv<<<384, 256, 0, stream>>>(x, WT, sp, qws, knew, vnew);
    k_attn<<<BB * HH * NSPLIT, 256, 0, stream>>>(qws, knew, vnew, ck, cv, Opart, lpart);
    k_oproj<<<256, 256, 0, stream>>>(Opart, lpart, WT + (size_t)3 * 1024 * 1024, out);
}

// Round 13
// 84.090 us; speedup vs baseline: 1.1610x; 1.1610x over previous
//
#include <hip/hip_runtime.h>
#include <hip/hip_bf16.h>
#include <math.h>

typedef __attribute__((ext_vector_type(8))) __bf16 bf16x8;
typedef __attribute__((ext_vector_type(4))) __bf16 bf16x4;
typedef __attribute__((ext_vector_type(4))) float f32x4;

#define EE 1024
#define HH 16
#define DD 64
#define BB 8
#define TT 64
#define NSPLIT 8

__device__ __forceinline__ f32x4 mfma16(bf16x8 a, bf16x8 b, f32x4 c) {
    return __builtin_amdgcn_mfma_f32_16x16x32_bf16(a, b, c, 0, 0, 0);
}

// ---- prep: weight transpose+convert only (WT[w][n][k] bf16) ----
__global__ __launch_bounds__(256) void k_prep(const float* __restrict__ Wq, const float* __restrict__ Wk,
                                              const float* __restrict__ Wv, const float* __restrict__ Wo,
                                              __bf16* __restrict__ WT) {
    __shared__ float tile[64][68];
    int bid = blockIdx.x;           // 0..1023
    int w = bid >> 8, tl = bid & 255;
    int k0 = (tl >> 4) * 64, n0 = (tl & 15) * 64;
    const float* W = (w == 0) ? Wq : (w == 1) ? Wk : (w == 2) ? Wv : Wo;
    int tid = threadIdx.x;
#pragma unroll
    for (int p = 0; p < 4; ++p) {
        int idx = p * 256 + tid;
        int r = idx >> 4, c4 = (idx & 15) * 4;
        float4 f = *(const float4*)&W[(size_t)(k0 + r) * EE + n0 + c4];
        *(float4*)&tile[r][c4] = f;
    }
    __syncthreads();
    __bf16* out = WT + (size_t)w * EE * EE;
#pragma unroll
    for (int p = 0; p < 2; ++p) {
        int q = p * 256 + tid;
        int r = q >> 3, c8 = (q & 7) * 8;
        bf16x8 v;
#pragma unroll
        for (int j = 0; j < 8; ++j) v[j] = (__bf16)tile[c8 + j][r];
        *(bf16x8*)&out[(size_t)(n0 + r) * EE + k0 + c8] = v;
    }
}

// ---- fused QKV projection + RoPE: x read f32-direct (A), WT bf16 (B) ----
// grid = 384, XCD-swizzled; R4 loop structure (pre-barrier prefetch).
__global__ __launch_bounds__(256) void k_qkv(const float* __restrict__ x, const __bf16* __restrict__ WT,
                                             const int* __restrict__ sp_ptr,
                                             __bf16* __restrict__ qws, __bf16* __restrict__ knew,
                                             __bf16* __restrict__ vnew) {
    __shared__ __bf16 a_lds[64][72];
    __shared__ __bf16 b_lds[64][72];
    __shared__ float cs_l[32], sn_l[32];
    int xcd = blockIdx.x & 7, idx = blockIdx.x >> 3;
    int bn = xcd * 6 + idx % 6;
    int bm = idx / 6;
    int wsel = bn >> 4;              // 0=q, 1=k, 2=v
    int n0 = (bn & 15) * 64;
    int m0 = bm * 64;
    const __bf16* Wt = WT + (size_t)wsel * EE * EE;
    int tid = threadIdx.x;
    int wv = tid >> 6, lane = tid & 63;
    int l16 = lane & 15, lhi = lane >> 4;
    int g = tid >> 4, m4 = (tid & 15) * 4;   // A staging (f32 rows)
    int r0 = tid >> 3, c8 = (tid & 7) * 8;   // B staging (bf16 rows)

    f32x4 acc[4];
#pragma unroll
    for (int f = 0; f < 4; ++f) acc[f] = (f32x4){0.f, 0.f, 0.f, 0.f};

    // prologue loads for kt=0
    f32x4 areg[4];
    bf16x8 br0, br1;
#pragma unroll
    for (int p = 0; p < 4; ++p)
        areg[p] = *(const f32x4*)&x[(size_t)(m0 + p * 16 + g) * EE + m4];
    br0 = *(const bf16x8*)&Wt[(size_t)(n0 + r0) * EE + c8];
    br1 = *(const bf16x8*)&Wt[(size_t)(n0 + 32 + r0) * EE + c8];

    // RoPE table for this block's single head
    if (tid < 32) {
        int h = bn & 15;
        int sp = sp_ptr[0];
        float invf = powf(10000.0f, -(float)tid / 32.0f);
        float ang = (float)(sp + h) * invf;
        float s, c;
        sincosf(ang, &s, &c);
        cs_l[tid] = c;
        sn_l[tid] = s;
    }

    for (int kt = 0; kt < 16; ++kt) {
        __syncthreads();
#pragma unroll
        for (int p = 0; p < 4; ++p) {
            bf16x4 a4 = { (__bf16)areg[p][0], (__bf16)areg[p][1], (__bf16)areg[p][2], (__bf16)areg[p][3] };
            *(bf16x4*)&a_lds[p * 16 + g][m4] = a4;
        }
        *(bf16x8*)&b_lds[r0][c8] = br0;
        *(bf16x8*)&b_lds[32 + r0][c8] = br1;
        if (kt < 15) {               // pre-barrier prefetch (R4-proven position)
            int ko = (kt + 1) * 64;
#pragma unroll
            for (int p = 0; p < 4; ++p)
                areg[p] = *(const f32x4*)&x[(size_t)(m0 + p * 16 + g) * EE + ko + m4];
            br0 = *(const bf16x8*)&Wt[(size_t)(n0 + r0) * EE + ko + c8];
            br1 = *(const bf16x8*)&Wt[(size_t)(n0 + 32 + r0) * EE + ko + c8];
        }
        __syncthreads();
        bf16x8 a0 = *(bf16x8*)&a_lds[wv * 16 + l16][lhi * 8];
        bf16x8 a1 = *(bf16x8*)&a_lds[wv * 16 + l16][32 + lhi * 8];
#pragma unroll
        for (int f = 0; f < 4; ++f) {
            bf16x8 b0 = *(bf16x8*)&b_lds[f * 16 + l16][lhi * 8];
            bf16x8 b1 = *(bf16x8*)&b_lds[f * 16 + l16][32 + lhi * 8];
            acc[f] = mfma16(a0, b0, acc[f]);
            acc[f] = mfma16(a1, b1, acc[f]);
        }
    }
    __bf16* dst = (wsel == 0) ? qws : (wsel == 1) ? knew : vnew;
    int h = bn & 15;
#pragma unroll
    for (int f = 0; f < 4; ++f) {
#pragma unroll
        for (int r = 0; r < 4; ++r) {
            float v = acc[f][r];
            int row = m0 + wv * 16 + lhi * 4 + r;
            int d = f * 16 + l16;
            float o = v;
            if (wsel < 2) {
                float other = __shfl_xor(v, 1);   // partner column (d^1) same row
                int pp = d >> 1;
                float c = cs_l[pp], s = sn_l[pp];
                o = ((d & 1) == 0) ? (v * c - other * s) : (other * s + v * c);
            }
            int b = row >> 6, t = row & 63;
            dst[((size_t)((b * HH + h) * TT + t)) * DD + d] = (__bf16)o;
        }
    }
}

// ---- flash-decoding attention: R4 structure + no-max softmax ----
// grid = B*H*NSPLIT (=1024, 4 blocks/CU), block = 256 (4 waves)
__global__ __launch_bounds__(256, 4) void k_attn(const __bf16* __restrict__ qws, const __bf16* __restrict__ knew,
                                                 const __bf16* __restrict__ vnew,
                                                 const float* __restrict__ ck, const float* __restrict__ cv,
                                                 __bf16* __restrict__ Opart, float* __restrict__ lpart) {
    __shared__ __bf16 k_lds[64][72];    // [s][d]
    __shared__ __bf16 vT_lds[64][68];   // [d][s]
    __shared__ __bf16 p_lds[64][72];    // [t][s] (wave-local rows)
    int bh = blockIdx.x >> 3, split = blockIdx.x & 7;
    int b = bh >> 4, h = bh & 15;
    int tid = threadIdx.x, wv = tid >> 6, lane = tid & 63;
    int l16 = lane & 15, lhi = lane >> 4;
    int g = tid >> 4, m4 = (tid & 15) * 4;   // staging coords

    bf16x8 qf0, qf1;
    {
        const __bf16* qp = qws + ((size_t)bh * TT + (wv * 16 + l16)) * DD;
        qf0 = *(const bf16x8*)&qp[lhi * 8];
        qf1 = *(const bf16x8*)&qp[32 + lhi * 8];
    }
    f32x4 acc[4];
#pragma unroll
    for (int f = 0; f < 4; ++f) acc[f] = (f32x4){0.f, 0.f, 0.f, 0.f};
    float l[4] = {0.f, 0.f, 0.f, 0.f};

    const float* ckb = ck + (size_t)b * 8192 * EE + h * DD;   // row stride EE floats
    const float* cvb = cv + (size_t)b * 8192 * EE + h * DD;
    int s0 = split * 512;

    auto compute = [&](bool mask) {
        f32x4 sf[4];
#pragma unroll
        for (int f = 0; f < 4; ++f) {
            f32x4 z = (f32x4){0.f, 0.f, 0.f, 0.f};
            bf16x8 b0 = *(bf16x8*)&k_lds[f * 16 + l16][lhi * 8];
            bf16x8 b1 = *(bf16x8*)&k_lds[f * 16 + l16][32 + lhi * 8];
            z = mfma16(qf0, b0, z);
            z = mfma16(qf1, b1, z);
            sf[f] = z;
        }
        const float SC = 0.125f * 1.44269504f;   // scale * log2(e)
#pragma unroll
        for (int f = 0; f < 4; ++f) {
#pragma unroll
            for (int r = 0; r < 4; ++r) {
                float sv = sf[f][r] * SC;
                if (mask) {
                    int t_row = wv * 16 + lhi * 4 + r;
                    int s_loc = f * 16 + l16;
                    if (s_loc > t_row) sv = -1e30f;
                }
                float pv = exp2f(sv);
                sf[f][r] = pv;
                l[r] += pv;          // per-lane partial; reduced once at kernel end
            }
        }
#pragma unroll
        for (int f = 0; f < 4; ++f)
#pragma unroll
            for (int r = 0; r < 4; ++r)
                p_lds[wv * 16 + lhi * 4 + r][f * 16 + l16] = (__bf16)sf[f][r];
        bf16x8 pa0 = *(bf16x8*)&p_lds[wv * 16 + l16][lhi * 8];
        bf16x8 pa1 = *(bf16x8*)&p_lds[wv * 16 + l16][32 + lhi * 8];
#pragma unroll
        for (int f = 0; f < 4; ++f) {
            bf16x8 v0 = *(bf16x8*)&vT_lds[f * 16 + l16][lhi * 8];
            bf16x8 v1 = *(bf16x8*)&vT_lds[f * 16 + l16][32 + lhi * 8];
            acc[f] = mfma16(pa0, v0, acc[f]);
            acc[f] = mfma16(pa1, v1, acc[f]);
        }
    };

    // prefetch tile 0: K rows g+16p, V rows 4g+i (consecutive, for in-reg transpose)
    f32x4 kreg[4], vreg[4];
#pragma unroll
    for (int p = 0; p < 4; ++p)
        kreg[p] = *(const f32x4*)&ckb[(size_t)(s0 + p * 16 + g) * EE + m4];
#pragma unroll
    for (int i = 0; i < 4; ++i)
        vreg[i] = *(const f32x4*)&cvb[(size_t)(s0 + 4 * g + i) * EE + m4];

    for (int it = 0; it < 8; ++it) {
#pragma unroll
        for (int p = 0; p < 4; ++p) {
            bf16x4 k4 = { (__bf16)kreg[p][0], (__bf16)kreg[p][1], (__bf16)kreg[p][2], (__bf16)kreg[p][3] };
            *(bf16x4*)&k_lds[p * 16 + g][m4] = k4;
        }
#pragma unroll
        for (int j = 0; j < 4; ++j) {
            bf16x4 tv = { (__bf16)vreg[0][j], (__bf16)vreg[1][j], (__bf16)vreg[2][j], (__bf16)vreg[3][j] };
            *(bf16x4*)&vT_lds[m4 + j][4 * g] = tv;
        }
        if (it < 7) {                // pre-barrier prefetch (R4-proven position)
            int sb = s0 + (it + 1) * 64;
#pragma unroll
            for (int p = 0; p < 4; ++p)
                kreg[p] = *(const f32x4*)&ckb[(size_t)(sb + p * 16 + g) * EE + m4];
#pragma unroll
            for (int i = 0; i < 4; ++i)
                vreg[i] = *(const f32x4*)&cvb[(size_t)(sb + 4 * g + i) * EE + m4];
        }
        __syncthreads();
        compute(false);
        __syncthreads();
    }

    if (split == 7) {
#pragma unroll
        for (int p = 0; p < 2; ++p) {
            int idx = p * 256 + tid;
            int r = idx >> 3, c8 = (idx & 7) * 8;
            *(bf16x8*)&k_lds[r][c8] = *(const bf16x8*)&knew[((size_t)bh * TT + r) * DD + c8];
            bf16x8 vf = *(const bf16x8*)&vnew[((size_t)bh * TT + r) * DD + c8];
#pragma unroll
            for (int j = 0; j < 8; ++j) vT_lds[c8 + j][r] = vf[j];
        }
        __syncthreads();
        compute(true);
    }

    // one deferred l-reduce across the 16-lane column group
#pragma unroll
    for (int off = 1; off < 16; off <<= 1) {
#pragma unroll
        for (int r = 0; r < 4; ++r) l[r] += __shfl_xor(l[r], off);
    }

    // store partials (bf16 unnormalized O, float l)
#pragma unroll
    for (int f = 0; f < 4; ++f)
#pragma unroll
        for (int r = 0; r < 4; ++r) {
            int t = wv * 16 + lhi * 4 + r;
            int d = f * 16 + l16;
            Opart[(((size_t)split * 128 + bh) * TT + t) * DD + d] = (__bf16)acc[f][r];
        }
    if (l16 == 0) {
#pragma unroll
        for (int r = 0; r < 4; ++r) {
            int t = wv * 16 + lhi * 4 + r;
            lpart[((size_t)split * 128 + bh) * TT + t] = l[r];
        }
    }
}

// ---- combine split partials (no-max: plain sums) -> ctx bf16, vectorized ----
// grid = 256, block = 256; each thread handles 8 consecutive d.
__global__ __launch_bounds__(256) void k_combine(const __bf16* __restrict__ Opart, const float* __restrict__ lpart,
                                                 __bf16* __restrict__ ctxb) {
    int idx = blockIdx.x * 256 + threadIdx.x;   // 65536 threads
    int d8 = idx & 7, t = (idx >> 3) & 63, bh = idx >> 9;
    float den = 0.f, num[8];
#pragma unroll
    for (int j = 0; j < 8; ++j) num[j] = 0.f;
#pragma unroll
    for (int s = 0; s < NSPLIT; ++s) {
        den += lpart[((size_t)s * 128 + bh) * TT + t];
        bf16x8 o = *(const bf16x8*)&Opart[(((size_t)s * 128 + bh) * TT + t) * DD + d8 * 8];
#pragma unroll
        for (int j = 0; j < 8; ++j) num[j] += (float)o[j];
    }
    float inv = 1.0f / den;
    bf16x8 c;
#pragma unroll
    for (int j = 0; j < 8; ++j) c[j] = (__bf16)(num[j] * inv);
    int b = bh >> 4, h = bh & 15;
    *(bf16x8*)&ctxb[(size_t)(b * TT + t) * EE + h * DD + d8 * 8] = c;
}

// ---- output projection: out = ctx @ Wo (WT-based, R4 exact) ----
__global__ __launch_bounds__(256) void k_oproj(const __bf16* __restrict__ ctxb, const __bf16* __restrict__ WoT,
                                               float* __restrict__ out) {
    __shared__ __bf16 a_lds[64][72];
    __shared__ __bf16 b_lds[64][72];
    int xcd = blockIdx.x & 7, idx = blockIdx.x >> 3;
    int bn = xcd * 2 + (idx & 1);
    int bm = idx >> 1;
    int n0 = bn * 64, m0 = bm * 64;
    int tid = threadIdx.x;
    int wv = tid >> 6, lane = tid & 63;
    int l16 = lane & 15, lhi = lane >> 4;
    int r0 = tid >> 3, c8 = (tid & 7) * 8;
    f32x4 acc[4];
#pragma unroll
    for (int f = 0; f < 4; ++f) acc[f] = (f32x4){0.f, 0.f, 0.f, 0.f};

    bf16x8 ar0 = *(const bf16x8*)&ctxb[(size_t)(m0 + r0) * EE + c8];
    bf16x8 ar1 = *(const bf16x8*)&ctxb[(size_t)(m0 + 32 + r0) * EE + c8];
    bf16x8 br0 = *(const bf16x8*)&WoT[(size_t)(n0 + r0) * EE + c8];
    bf16x8 br1 = *(const bf16x8*)&WoT[(size_t)(n0 + 32 + r0) * EE + c8];

    for (int kt = 0; kt < 16; ++kt) {
        __syncthreads();
        *(bf16x8*)&a_lds[r0][c8] = ar0;
        *(bf16x8*)&a_lds[32 + r0][c8] = ar1;
        *(bf16x8*)&b_lds[r0][c8] = br0;
        *(bf16x8*)&b_lds[32 + r0][c8] = br1;
        if (kt < 15) {
            int ko = (kt + 1) * 64;
            ar0 = *(const bf16x8*)&ctxb[(size_t)(m0 + r0) * EE + ko + c8];
            ar1 = *(const bf16x8*)&ctxb[(size_t)(m0 + 32 + r0) * EE + ko + c8];
            br0 = *(const bf16x8*)&WoT[(size_t)(n0 + r0) * EE + ko + c8];
            br1 = *(const bf16x8*)&WoT[(size_t)(n0 + 32 + r0) * EE + ko + c8];
        }
        __syncthreads();
        bf16x8 a0 = *(bf16x8*)&a_lds[wv * 16 + l16][lhi * 8];
        bf16x8 a1 = *(bf16x8*)&a_lds[wv * 16 + l16][32 + lhi * 8];
#pragma unroll
        for (int f = 0; f < 4; ++f) {
            bf16x8 b0 = *(bf16x8*)&b_lds[f * 16 + l16][lhi * 8];
            bf16x8 b1 = *(bf16x8*)&b_lds[f * 16 + l16][32 + lhi * 8];
            acc[f] = mfma16(a0, b0, acc[f]);
            acc[f] = mfma16(a1, b1, acc[f]);
        }
    }
#pragma unroll
    for (int f = 0; f < 4; ++f)
#pragma unroll
        for (int r = 0; r < 4; ++r) {
            int row = m0 + wv * 16 + lhi * 4 + r;
            out[(size_t)row * EE + n0 + f * 16 + l16] = acc[f][r];
        }
}

extern "C" void kernel_launch(void* const* d_in, const int* in_sizes, int n_in,
                              void* d_out, int out_size, void* d_ws, size_t ws_size,
                              hipStream_t stream) {
    const float* x  = (const float*)d_in[0];
    const float* ck = (const float*)d_in[1];
    const float* cv = (const float*)d_in[2];
    const float* Wq = (const float*)d_in[3];
    const float* Wk = (const float*)d_in[4];
    const float* Wv = (const float*)d_in[5];
    const float* Wo = (const float*)d_in[6];
    const int* sp   = (const int*)d_in[7];
    float* out = (float*)d_out;

    char* p = (char*)d_ws;
    __bf16* WT = (__bf16*)p;            p += (size_t)4 * 1024 * 1024 * 2;
    __bf16* qws = (__bf16*)p;           p += (size_t)524288 * 2;
    __bf16* knew = (__bf16*)p;          p += (size_t)524288 * 2;
    __bf16* vnew = (__bf16*)p;          p += (size_t)524288 * 2;
    __bf16* Opart = (__bf16*)p;         p += (size_t)NSPLIT * 128 * 64 * 64 * 2;
    float* lpart = (float*)p;           p += (size_t)NSPLIT * 8192 * 4;
    __bf16* ctxb = (__bf16*)p;          p += (size_t)524288 * 2;

    k_prep<<<1024, 256, 0, stream>>>(Wq, Wk, Wv, Wo, WT);
    k_qkv<<<384, 256, 0, stream>>>(x, WT, sp, qws, knew, vnew);
    k_attn<<<BB * HH * NSPLIT, 256, 0, stream>>>(qws, knew, vnew, ck, cv, Opart, lpart);
    k_combine<<<256, 256, 0, stream>>>(Opart, lpart, ctxb);
    k_oproj<<<128, 256, 0, stream>>>(ctxb, WT + (size_t)3 * 1024 * 1024, out);
}